// Round 1
// baseline (190.635 us; speedup 1.0000x reference)
//
#include <hip/hip_runtime.h>
#include <hip/hip_bf16.h>
#include <cstdint>
#include <cstddef>

#define BDIM 64
#define SDIM 512
#define HDIM 1024
#define MTOT (BDIM * SDIM)  // 32768

typedef __attribute__((ext_vector_type(8))) short short8;
typedef __attribute__((ext_vector_type(4))) float f32x4;

__device__ __forceinline__ unsigned short f2bf(float f) {
  union { float f; unsigned int u; } x; x.f = f;
  unsigned int u = x.u;
  u += 0x7fffu + ((u >> 16) & 1u);  // round-to-nearest-even
  return (unsigned short)(u >> 16);
}

// Convert W2 = W[:, H:2H] (f32) -> bf16 [HDIM][HDIM], row h contiguous in k.
__global__ __launch_bounds__(256) void prep_w2_kernel(const float* __restrict__ W,
                                                      unsigned short* __restrict__ w2) {
  const int h = blockIdx.x;
  const int t = threadIdx.x;
  const float4 g = *reinterpret_cast<const float4*>(W + (size_t)h * 2048 + 1024 + t * 4);
  ushort4 o = make_ushort4(f2bf(g.x), f2bf(g.y), f2bf(g.z), f2bf(g.w));
  *reinterpret_cast<ushort4*>(w2 + (size_t)h * HDIM + t * 4) = o;
}

// A[b,h] = hidden[b,:] . W[h, 0:H] + bias[h]   (f32, exact-ish)
__global__ __launch_bounds__(256) void compute_a_kernel(const float* __restrict__ hidden,
                                                        const float* __restrict__ W,
                                                        const float* __restrict__ bias,
                                                        float* __restrict__ A) {
  const int hc = blockIdx.x;  // 0..3
  const int b  = blockIdx.y;  // 0..63
  const int t  = threadIdx.x;
  __shared__ float hl[HDIM];
  *reinterpret_cast<float4*>(&hl[t * 4]) =
      *reinterpret_cast<const float4*>(hidden + (size_t)b * HDIM + t * 4);
  __syncthreads();
  const int h = hc * 256 + t;
  const float* wr = W + (size_t)h * 2048;
  float acc = bias[h];
  for (int k = 0; k < HDIM; k += 4) {
    const float4 wv = *reinterpret_cast<const float4*>(wr + k);
    acc += wv.x * hl[k] + wv.y * hl[k + 1] + wv.z * hl[k + 2] + wv.w * hl[k + 3];
  }
  A[(size_t)b * HDIM + h] = acc;
}

// Main GEMM: C[m,n] = enc[m,:] . W2[n,:] (bf16 MFMA), fused epilogue:
// sp[nblk][m] = sum over this block's 128 n of v[n]*tanh(C[m,n] + A[b(m),n])
__global__ __launch_bounds__(256) void gemm_scores_kernel(const float* __restrict__ enc,
                                                          const unsigned short* __restrict__ w2,
                                                          const float* __restrict__ A,
                                                          const float* __restrict__ v,
                                                          float* __restrict__ sp) {
  __shared__ unsigned short As[128][32];
  __shared__ unsigned short Bs[128][32];

  // XCD-aware swizzle (2048 blocks, 8 XCDs, bijective since 2048 % 8 == 0):
  // groups of 256 consecutive logical blocks land on one XCD so the 8 N-blocks
  // sharing an Enc M-strip hit the same L2.
  const int lg = (int)((blockIdx.x & 7) * 256 + (blockIdx.x >> 3));
  const int nblk = lg & 7;
  const int mstrip = lg >> 3;
  const int m0 = mstrip * 128;
  const int n0 = nblk * 128;
  const int b = m0 >> 9;  // S=512 divides the 128-row strip into one b

  const int tid = threadIdx.x;
  const int w = tid >> 6, l = tid & 63;
  const int wm = w >> 1, wn = w & 1;
  const int lr = l & 15, lk = l >> 4;

  f32x4 zero = {0.f, 0.f, 0.f, 0.f};
  f32x4 acc[4][4];
#pragma unroll
  for (int fm = 0; fm < 4; ++fm)
#pragma unroll
    for (int fn = 0; fn < 4; ++fn) acc[fm][fn] = zero;

  for (int kk = 0; kk < HDIM; kk += 32) {
    __syncthreads();
    // Stage A-tile: enc f32 -> bf16 (reg-staged conversion), As[128][32]
#pragma unroll
    for (int i = 0; i < 4; ++i) {
      const int j = tid + i * 256;
      const int row = j >> 3, seg = j & 7;
      const float4 g = *reinterpret_cast<const float4*>(
          enc + (size_t)(m0 + row) * HDIM + kk + seg * 4);
      ushort4 h = make_ushort4(f2bf(g.x), f2bf(g.y), f2bf(g.z), f2bf(g.w));
      *reinterpret_cast<ushort4*>(&As[row][seg * 4]) = h;
    }
    // Stage B-tile: w2 already bf16, straight 16B copies, Bs[128][32]
#pragma unroll
    for (int i = 0; i < 2; ++i) {
      const int j = tid + i * 256;
      const int row = j >> 2, seg = j & 3;
      const uint4 g = *reinterpret_cast<const uint4*>(
          w2 + (size_t)(n0 + row) * HDIM + kk + seg * 8);
      *reinterpret_cast<uint4*>(&Bs[row][seg * 8]) = g;
    }
    __syncthreads();

    short8 af[4], bfr[4];
#pragma unroll
    for (int f = 0; f < 4; ++f) {
      af[f]  = *reinterpret_cast<const short8*>(&As[wm * 64 + f * 16 + lr][lk * 8]);
      bfr[f] = *reinterpret_cast<const short8*>(&Bs[wn * 64 + f * 16 + lr][lk * 8]);
    }
#pragma unroll
    for (int fm = 0; fm < 4; ++fm)
#pragma unroll
      for (int fn = 0; fn < 4; ++fn)
        acc[fm][fn] = __builtin_amdgcn_mfma_f32_16x16x32_bf16(af[fm], bfr[fn], acc[fm][fn], 0, 0, 0);
  }

  // Epilogue: e = tanh(C + A), dot with v over this block's n-range, reduce.
  const float* Ab = A + (size_t)b * HDIM + n0;
  const float* vb = v + n0;
  float a_n[4], v_n[4];
#pragma unroll
  for (int fn = 0; fn < 4; ++fn) {
    const int n = wn * 64 + fn * 16 + lr;
    a_n[fn] = Ab[n];
    v_n[fn] = vb[n];
  }
  float part[4][4];
#pragma unroll
  for (int fm = 0; fm < 4; ++fm) {
#pragma unroll
    for (int r = 0; r < 4; ++r) {
      float s = 0.f;
#pragma unroll
      for (int fn = 0; fn < 4; ++fn)
        s += v_n[fn] * tanhf(acc[fm][fn][r] + a_n[fn]);
      // reduce across the 16 lanes (lr) sharing the same output row
      s += __shfl_xor(s, 1);
      s += __shfl_xor(s, 2);
      s += __shfl_xor(s, 4);
      s += __shfl_xor(s, 8);
      part[fm][r] = s;  // full sum over this wave's 64 n-values
    }
  }
  __syncthreads();
  float* red = reinterpret_cast<float*>(&As[0][0]);  // 128 floats, reuse LDS
  if (wn == 0 && lr == 0) {
#pragma unroll
    for (int fm = 0; fm < 4; ++fm)
#pragma unroll
      for (int r = 0; r < 4; ++r)
        red[wm * 64 + fm * 16 + lk * 4 + r] = part[fm][r];
  }
  __syncthreads();
  if (wn == 1 && lr == 0) {
#pragma unroll
    for (int fm = 0; fm < 4; ++fm)
#pragma unroll
      for (int r = 0; r < 4; ++r)
        red[wm * 64 + fm * 16 + lk * 4 + r] += part[fm][r];
  }
  __syncthreads();
  if (tid < 128) sp[(size_t)nblk * MTOT + m0 + tid] = red[tid];
}

// scores[b,s] = sum of 8 partials; softmax over s (512) per b; write weights.
__global__ __launch_bounds__(512) void softmax_kernel(const float* __restrict__ sp,
                                                      float* __restrict__ wts) {
  const int b = blockIdx.x, s = threadIdx.x;
  float sc = 0.f;
#pragma unroll
  for (int j = 0; j < 8; ++j) sc += sp[(size_t)j * MTOT + b * SDIM + s];
  float m = sc;
#pragma unroll
  for (int d = 1; d < 64; d <<= 1) m = fmaxf(m, __shfl_xor(m, d));
  __shared__ float redm[8], reds[8];
  if ((s & 63) == 0) redm[s >> 6] = m;
  __syncthreads();
  m = redm[0];
#pragma unroll
  for (int j = 1; j < 8; ++j) m = fmaxf(m, redm[j]);
  const float e = expf(sc - m);
  float sum = e;
#pragma unroll
  for (int d = 1; d < 64; d <<= 1) sum += __shfl_xor(sum, d);
  if ((s & 63) == 0) reds[s >> 6] = sum;
  __syncthreads();
  float tot = 0.f;
#pragma unroll
  for (int j = 0; j < 8; ++j) tot += reds[j];
  wts[(size_t)b * SDIM + s] = e / tot;
}

// context[b,h] = sum_s w[b,s] * enc[b,s,h]
__global__ __launch_bounds__(256) void context_kernel(const float* __restrict__ enc,
                                                      const float* __restrict__ wts,
                                                      float* __restrict__ ctx) {
  const int hc = blockIdx.x;  // 0..3
  const int b  = blockIdx.y;  // 0..63
  const int t  = threadIdx.x;
  __shared__ float wl[SDIM];
  wl[t] = wts[(size_t)b * SDIM + t];
  wl[t + 256] = wts[(size_t)b * SDIM + 256 + t];
  __syncthreads();
  const int h = hc * 256 + t;
  const float* e0 = enc + (size_t)b * SDIM * HDIM + h;
  float acc0 = 0.f, acc1 = 0.f;
  for (int s = 0; s < SDIM; s += 2) {
    acc0 += wl[s] * e0[(size_t)s * HDIM];
    acc1 += wl[s + 1] * e0[(size_t)(s + 1) * HDIM];
  }
  ctx[(size_t)b * HDIM + h] = acc0 + acc1;
}

extern "C" void kernel_launch(void* const* d_in, const int* in_sizes, int n_in,
                              void* d_out, int out_size, void* d_ws, size_t ws_size,
                              hipStream_t stream) {
  const float* hidden = (const float*)d_in[0];
  const float* enc    = (const float*)d_in[1];
  const float* W      = (const float*)d_in[2];
  const float* bias   = (const float*)d_in[3];
  const float* v      = (const float*)d_in[4];

  float* ctx = (float*)d_out;                     // [64*1024] context
  float* wts = (float*)d_out + BDIM * HDIM;       // [64*512] attention weights

  char* ws = (char*)d_ws;
  unsigned short* w2 = (unsigned short*)ws;                                   // 2 MB
  float* A  = (float*)(ws + (size_t)2 * 1024 * 1024);                         // 256 KB
  float* sp = (float*)(ws + (size_t)2 * 1024 * 1024 + 256 * 1024);            // 1 MB

  hipLaunchKernelGGL(prep_w2_kernel, dim3(1024), dim3(256), 0, stream, W, w2);
  hipLaunchKernelGGL(compute_a_kernel, dim3(4, 64), dim3(256), 0, stream, hidden, W, bias, A);
  hipLaunchKernelGGL(gemm_scores_kernel, dim3(2048), dim3(256), 0, stream, enc, w2, A, v, sp);
  hipLaunchKernelGGL(softmax_kernel, dim3(64), dim3(512), 0, stream, sp, wts);
  hipLaunchKernelGGL(context_kernel, dim3(4, 64), dim3(256), 0, stream, enc, wts, ctx);
}

// Round 2
// 187.552 us; speedup vs baseline: 1.0164x; 1.0164x over previous
//
#include <hip/hip_runtime.h>
#include <hip/hip_bf16.h>
#include <cstdint>
#include <cstddef>

#define BDIM 64
#define SDIM 512
#define HDIM 1024
#define MTOT (BDIM * SDIM)  // 32768

typedef __attribute__((ext_vector_type(8))) short short8;
typedef __attribute__((ext_vector_type(4))) float f32x4;

// HW packed f32->bf16 RNE convert (T12 recipe; no builtin on gfx950).
__device__ __forceinline__ unsigned int cvt2(float a, float b) {
  unsigned int r;
  asm("v_cvt_pk_bf16_f32 %0, %1, %2" : "=v"(r) : "v"(a), "v"(b));
  return r;
}

__device__ __forceinline__ void gld_lds16(const void* g, void* l) {
  __builtin_amdgcn_global_load_lds(
      (const __attribute__((address_space(1))) unsigned int*)g,
      (__attribute__((address_space(3))) unsigned int*)l, 16, 0, 0);
}

// W2 = W[:, H:2H] -> bf16, tile-major + XOR-swizzled layout in ws:
// tile (nblk, kt) is 128 rows x 8 granules(16B); logical granule g of row r
// stored at slot g ^ (r&7).  Linear global_load_lds then reproduces the
// swizzled image in LDS (rule #21: inverse-swz source + swz read).
__global__ __launch_bounds__(256) void prep_w2_kernel(const float* __restrict__ W,
                                                      char* __restrict__ w2s) {
  const int n = blockIdx.x * 2 + (threadIdx.x >> 7);
  const int g = threadIdx.x & 127;  // granule 0..127 along k
  const int kt = g >> 3, gi = g & 7;
  const float* src = W + (size_t)n * 2048 + 1024 + g * 8;
  const float4 f0 = *reinterpret_cast<const float4*>(src);
  const float4 f1 = *reinterpret_cast<const float4*>(src + 4);
  uint4 u = make_uint4(cvt2(f0.x, f0.y), cvt2(f0.z, f0.w),
                       cvt2(f1.x, f1.y), cvt2(f1.z, f1.w));
  const int nblk = n >> 7, row = n & 127;
  const size_t off = ((size_t)(nblk * 16 + kt) * 128 + row) * 128 +
                     (size_t)(gi ^ (row & 7)) * 16;
  *reinterpret_cast<uint4*>(w2s + off) = u;
}

// A[b,h] = hidden[b,:] . W[h, 0:H] + bias[h]   (f32)
__global__ __launch_bounds__(256) void compute_a_kernel(const float* __restrict__ hidden,
                                                        const float* __restrict__ W,
                                                        const float* __restrict__ bias,
                                                        float* __restrict__ A) {
  const int hc = blockIdx.x;
  const int b  = blockIdx.y;
  const int t  = threadIdx.x;
  __shared__ float hl[HDIM];
  *reinterpret_cast<float4*>(&hl[t * 4]) =
      *reinterpret_cast<const float4*>(hidden + (size_t)b * HDIM + t * 4);
  __syncthreads();
  const int h = hc * 256 + t;
  const float* wr = W + (size_t)h * 2048;
  float acc = bias[h];
  for (int k = 0; k < HDIM; k += 4) {
    const float4 wv = *reinterpret_cast<const float4*>(wr + k);
    acc += wv.x * hl[k] + wv.y * hl[k + 1] + wv.z * hl[k + 2] + wv.w * hl[k + 3];
  }
  A[(size_t)b * HDIM + h] = acc;
}

// Main GEMM (128x128 tile, BK=64, bf16 MFMA) + fused tanh.v epilogue.
__global__ __launch_bounds__(256) void gemm_scores_kernel(const float* __restrict__ enc,
                                                          const char* __restrict__ w2s,
                                                          const float* __restrict__ A,
                                                          const float* __restrict__ v,
                                                          float* __restrict__ sp) {
  __shared__ unsigned short As[128][64];  // 16 KB, XOR-swizzled granules
  __shared__ unsigned short Bs[128][64];  // 16 KB, XOR-swizzled granules

  // XCD-aware swizzle: 2048 blocks, 8 XCDs, bijective (2048 % 8 == 0).
  const int lg = (int)((blockIdx.x & 7) * 256 + (blockIdx.x >> 3));
  const int nblk = lg & 7;
  const int mstrip = lg >> 3;
  const int m0 = mstrip * 128;
  const int n0 = nblk * 128;
  const int b = m0 >> 9;

  const int tid = threadIdx.x;
  const int w = tid >> 6, l = tid & 63;
  const int wm = w >> 1, wn = w & 1;
  const int lr = l & 15, lk = l >> 4;

  char* AsB = reinterpret_cast<char*>(&As[0][0]);
  char* BsB = reinterpret_cast<char*>(&Bs[0][0]);

  f32x4 zero = {0.f, 0.f, 0.f, 0.f};
  f32x4 acc[4][4];
#pragma unroll
  for (int fm = 0; fm < 4; ++fm)
#pragma unroll
    for (int fn = 0; fn < 4; ++fn) acc[fm][fn] = zero;

  const char* wtile_base = w2s + ((size_t)nblk * 16) * 16384;

  for (int kt = 0; kt < 16; ++kt) {
    const int kk = kt * 64;
    __syncthreads();
    // --- Stage A: enc f32 -> bf16 via v_cvt_pk, write to swizzled slot ---
    const float* encb = enc + (size_t)m0 * HDIM + kk;
#pragma unroll
    for (int i = 0; i < 4; ++i) {
      const int j = tid + i * 256;
      const int row = j >> 3, g = j & 7;
      const float* src = encb + (size_t)row * HDIM + g * 8;
      const float4 f0 = *reinterpret_cast<const float4*>(src);
      const float4 f1 = *reinterpret_cast<const float4*>(src + 4);
      uint4 u = make_uint4(cvt2(f0.x, f0.y), cvt2(f0.z, f0.w),
                           cvt2(f1.x, f1.y), cvt2(f1.z, f1.w));
      *reinterpret_cast<uint4*>(AsB + row * 128 + (g ^ (row & 7)) * 16) = u;
    }
    // --- Stage B: swizzled image already in ws; linear 16B DMA to LDS ---
    const char* wtile = wtile_base + (size_t)kt * 16384;
#pragma unroll
    for (int c = 0; c < 4; ++c) {
      const int off = c * 4096 + w * 1024;
      gld_lds16(wtile + off + l * 16, BsB + off);
    }
    __syncthreads();

#pragma unroll
    for (int ks = 0; ks < 2; ++ks) {
      short8 af[4], bfr[4];
#pragma unroll
      for (int f = 0; f < 4; ++f) {
        const int ra = wm * 64 + f * 16 + lr;
        const int ga = (ks * 4 + lk) ^ (ra & 7);
        af[f] = *reinterpret_cast<const short8*>(AsB + ra * 128 + ga * 16);
        const int rb = wn * 64 + f * 16 + lr;
        const int gb = (ks * 4 + lk) ^ (rb & 7);
        bfr[f] = *reinterpret_cast<const short8*>(BsB + rb * 128 + gb * 16);
      }
#pragma unroll
      for (int fm = 0; fm < 4; ++fm)
#pragma unroll
        for (int fn = 0; fn < 4; ++fn)
          acc[fm][fn] = __builtin_amdgcn_mfma_f32_16x16x32_bf16(af[fm], bfr[fn], acc[fm][fn], 0, 0, 0);
    }
  }

  // Epilogue: e = tanh(C + A), dot with v over this block's n-range, reduce.
  const float* Ab = A + (size_t)b * HDIM + n0;
  const float* vb = v + n0;
  float a_n[4], v_n[4];
#pragma unroll
  for (int fn = 0; fn < 4; ++fn) {
    const int n = wn * 64 + fn * 16 + lr;
    a_n[fn] = Ab[n];
    v_n[fn] = vb[n];
  }
  float part[4][4];
#pragma unroll
  for (int fm = 0; fm < 4; ++fm) {
#pragma unroll
    for (int r = 0; r < 4; ++r) {
      float s = 0.f;
#pragma unroll
      for (int fn = 0; fn < 4; ++fn)
        s += v_n[fn] * tanhf(acc[fm][fn][r] + a_n[fn]);
      s += __shfl_xor(s, 1);
      s += __shfl_xor(s, 2);
      s += __shfl_xor(s, 4);
      s += __shfl_xor(s, 8);
      part[fm][r] = s;  // sum over this wave's 64 n-values
    }
  }
  __syncthreads();
  float* red = reinterpret_cast<float*>(&As[0][0]);
  if (wn == 0 && lr == 0) {
#pragma unroll
    for (int fm = 0; fm < 4; ++fm)
#pragma unroll
      for (int r = 0; r < 4; ++r)
        red[wm * 64 + fm * 16 + lk * 4 + r] = part[fm][r];
  }
  __syncthreads();
  if (wn == 1 && lr == 0) {
#pragma unroll
    for (int fm = 0; fm < 4; ++fm)
#pragma unroll
      for (int r = 0; r < 4; ++r)
        red[wm * 64 + fm * 16 + lk * 4 + r] += part[fm][r];
  }
  __syncthreads();
  if (tid < 128) sp[(size_t)nblk * MTOT + m0 + tid] = red[tid];
}

// scores[b,s] = sum of 8 partials; softmax over s (512) per b; write weights.
__global__ __launch_bounds__(512) void softmax_kernel(const float* __restrict__ sp,
                                                      float* __restrict__ wts) {
  const int b = blockIdx.x, s = threadIdx.x;
  float sc = 0.f;
#pragma unroll
  for (int j = 0; j < 8; ++j) sc += sp[(size_t)j * MTOT + b * SDIM + s];
  float m = sc;
#pragma unroll
  for (int d = 1; d < 64; d <<= 1) m = fmaxf(m, __shfl_xor(m, d));
  __shared__ float redm[8], reds[8];
  if ((s & 63) == 0) redm[s >> 6] = m;
  __syncthreads();
  m = redm[0];
#pragma unroll
  for (int j = 1; j < 8; ++j) m = fmaxf(m, redm[j]);
  const float e = expf(sc - m);
  float sum = e;
#pragma unroll
  for (int d = 1; d < 64; d <<= 1) sum += __shfl_xor(sum, d);
  if ((s & 63) == 0) reds[s >> 6] = sum;
  __syncthreads();
  float tot = 0.f;
#pragma unroll
  for (int j = 0; j < 8; ++j) tot += reds[j];
  wts[(size_t)b * SDIM + s] = e / tot;
}

// context[b,h] = sum_s w[b,s] * enc[b,s,h]
__global__ __launch_bounds__(256) void context_kernel(const float* __restrict__ enc,
                                                      const float* __restrict__ wts,
                                                      float* __restrict__ ctx) {
  const int hc = blockIdx.x;
  const int b  = blockIdx.y;
  const int t  = threadIdx.x;
  __shared__ float wl[SDIM];
  wl[t] = wts[(size_t)b * SDIM + t];
  wl[t + 256] = wts[(size_t)b * SDIM + 256 + t];
  __syncthreads();
  const int h = hc * 256 + t;
  const float* e0 = enc + (size_t)b * SDIM * HDIM + h;
  float acc0 = 0.f, acc1 = 0.f;
  for (int s = 0; s < SDIM; s += 2) {
    acc0 += wl[s] * e0[(size_t)s * HDIM];
    acc1 += wl[s + 1] * e0[(size_t)(s + 1) * HDIM];
  }
  ctx[(size_t)b * HDIM + h] = acc0 + acc1;
}

extern "C" void kernel_launch(void* const* d_in, const int* in_sizes, int n_in,
                              void* d_out, int out_size, void* d_ws, size_t ws_size,
                              hipStream_t stream) {
  const float* hidden = (const float*)d_in[0];
  const float* enc    = (const float*)d_in[1];
  const float* W      = (const float*)d_in[2];
  const float* bias   = (const float*)d_in[3];
  const float* v      = (const float*)d_in[4];

  float* ctx = (float*)d_out;                // [64*1024] context
  float* wts = (float*)d_out + BDIM * HDIM;  // [64*512] attention weights

  char* ws = (char*)d_ws;
  char* w2s = ws;                                                    // 2 MB swizzled tiles
  float* A  = (float*)(ws + (size_t)2 * 1024 * 1024);                // 256 KB
  float* sp = (float*)(ws + (size_t)2 * 1024 * 1024 + 256 * 1024);   // 1 MB

  hipLaunchKernelGGL(prep_w2_kernel, dim3(512), dim3(256), 0, stream, W, w2s);
  hipLaunchKernelGGL(compute_a_kernel, dim3(4, 64), dim3(256), 0, stream, hidden, W, bias, A);
  hipLaunchKernelGGL(gemm_scores_kernel, dim3(2048), dim3(256), 0, stream, enc, w2s, A, v, sp);
  hipLaunchKernelGGL(softmax_kernel, dim3(64), dim3(512), 0, stream, sp, wts);
  hipLaunchKernelGGL(context_kernel, dim3(4, 64), dim3(256), 0, stream, enc, wts, ctx);
}